// Round 3
// baseline (263.518 us; speedup 1.0000x reference)
//
#include <hip/hip_runtime.h>

#define NB 512
#define NV 64
#define ND 32
#define NH 64
#define NE 4032

typedef short s16x8 __attribute__((ext_vector_type(8)));
typedef float f32x4 __attribute__((ext_vector_type(4)));
typedef unsigned int u32;

#define HLOG2PI 0.9189385332046727f
#define LOG2C   0.6931471805599453f

__device__ __forceinline__ unsigned short f2bf(float f){
  u32 u = __float_as_uint(f);
  u += 0x7FFFu + ((u >> 16) & 1u);
  return (unsigned short)(u >> 16);
}

// packed f32x2 -> bf16x2 (RNE)
__device__ __forceinline__ u32 pk2(float a, float b){
  return (u32)f2bf(a) | ((u32)f2bf(b) << 16);
}

// async global->LDS, 16B per lane; lds dst = wave-uniform base + lane*16
__device__ __forceinline__ void gload16(const void* g, void* l){
  __builtin_amdgcn_global_load_lds(
      (const __attribute__((address_space(1))) void*)g,
      (__attribute__((address_space(3))) void*)l, 16, 0, 0);
}

// ---------------- setup kernels ---------------------------------------------

__global__ __launch_bounds__(256) void k_bucket(const int* __restrict__ recv,
                                               const int* __restrict__ send,
                                               int* __restrict__ ebyv,
                                               int* __restrict__ sbyv){
  __shared__ int cnt[NV];
  int t = threadIdx.x;
  if (t < NV) cnt[t] = 0;
  __syncthreads();
  for (int e = t; e < NE; e += 256){
    int v = recv[e];
    int p = atomicAdd(&cnt[v], 1);
    ebyv[v*64 + p] = e;
    sbyv[v*64 + p] = send[e];
  }
  __syncthreads();
  if (t < NV){
    for (int s = cnt[t]; s < 64; s++){ ebyv[t*64 + s] = -1; sbyv[t*64 + s] = t; }
  }
}

// x (fp32) -> bf16, 8 elems/thread
__global__ __launch_bounds__(256) void k_xbf(const float* __restrict__ x,
                                             uint4* __restrict__ xbf){
  int i = blockIdx.x*256 + threadIdx.x;
  const float4* s = (const float4*)x + i*2;
  float4 a = s[0], b = s[1];
  xbf[i] = make_uint4(pk2(a.x,a.y), pk2(a.z,a.w), pk2(b.x,b.y), pk2(b.z,b.w));
}

// bf16-convert + transpose + XOR-swizzle all weight matrices into ws.
// col j: element k at j*RL + ((k>>3)^(j&7))*8 + (k&7)
__global__ __launch_bounds__(256) void k_prep(
    const float* __restrict__ m1w, const float* __restrict__ m2w,
    const float* __restrict__ f1w, const float* __restrict__ f2w,
    const float* __restrict__ muw, const float* __restrict__ lsw,
    unsigned short* __restrict__ W1s, unsigned short* __restrict__ W2s,
    unsigned short* __restrict__ F1s, unsigned short* __restrict__ F2s,
    unsigned short* __restrict__ HWs)
{
  int m = blockIdx.y;
  int idx = blockIdx.x*256 + threadIdx.x;
  if (m == 0){
    if (idx < 4096){ int k = idx>>6, j = idx&63;
      W1s[j*64 + (((k>>3)^(j&7))<<3) + (k&7)] = f2bf(m1w[idx]); }
  } else if (m == 1){
    if (idx < 4096){ int k = idx>>6, j = idx&63;
      W2s[j*64 + (((k>>3)^(j&7))<<3) + (k&7)] = f2bf(m2w[idx]); }
  } else if (m == 2){
    if (idx < 6144){ int k = idx>>6, j = idx&63;   // fc1_w [96][64]
      F1s[j*128 + (((k>>3)^(j&7))<<3) + (k&7)] = f2bf(f1w[idx]); }
  } else if (m == 3){
    if (idx < 4096){ int k = idx>>6, j = idx&63;
      F2s[j*64 + (((k>>3)^(j&7))<<3) + (k&7)] = f2bf(f2w[idx]); }
  } else {
    if (idx < 1024){ int k = idx>>4, j = idx&15;   // head cols: 0..7 mu, 8..15 ls
      float s = (j < 8) ? muw[k*8 + j] : lsw[k*8 + (j-8)];
      HWs[j*64 + (((k>>3)^(j&7))<<3) + (k&7)] = f2bf(s); }
  }
}

// ---------------- kernel 1: edge MLP grouped by receiver ---------------------
// one block per (b,v). Transposed GEMMs: out^T = W^T @ In^T, so A-frag = W
// (col-major staged), B-frag = rows of In (row-major LDS), C cols = edge rows.

__global__ __launch_bounds__(256) void k_msg(
    const unsigned short* __restrict__ xbf, const float* __restrict__ x,
    const float* __restrict__ edges,
    const int* __restrict__ ebyv, const int* __restrict__ sbyv,
    const unsigned short* __restrict__ Wg,
    const float* __restrict__ b1g, const float* __restrict__ b2g,
    float* __restrict__ out_aug)
{
  __shared__ __align__(16) unsigned short A1[64*64];   // [edge-row][K] swz
  __shared__ __align__(16) unsigned short Hs[64*64];   // [edge-row][H] swz
  __shared__ __align__(16) unsigned short Wl[2*64*64]; // W1 | W2
  __shared__ float wrow[64];
  __shared__ float aggp[4][64];

  const int tid = threadIdx.x;
  const int w = tid >> 6, lane = tid & 63;
  const int l16 = lane & 15, l4 = lane >> 4;
  const int b = blockIdx.x >> 6, v = blockIdx.x & 63;

  if (tid < 64){
    int e = ebyv[v*64 + tid];
    float we = 0.0f;
    if (e >= 0) we = edges[(b*NE + e)*2 + 1];
    wrow[tid] = we;
  }

  // stage W1|W2: 1024 x 16B chunks, linear
  {
    char* lb = (char*)Wl + w*64*16;
    #pragma unroll
    for (int i = 0; i < 4; i++)
      gload16(Wg + (i*256 + w*64 + lane)*8, lb + i*256*16);
  }
  // stage A1: row = edge slot, cols 0..31 = x[b,v], 32..63 = x[b,send].
  // LDS linear dest; swizzle achieved by permuting the SOURCE chunk index.
  {
    char* lb = (char*)A1 + w*64*16;
    #pragma unroll
    for (int i = 0; i < 2; i++){
      int g = i*256 + tid;
      int row = g >> 3;
      int c = (g & 7) ^ (row & 7);
      const unsigned short* src = (c < 4)
          ? (xbf + (b*NV + v)*ND + c*8)
          : (xbf + (b*NV + sbyv[v*64 + row])*ND + (c-4)*8);
      gload16(src, lb + i*256*16);
    }
  }

  // biases for this thread's j = t*16 + l4*4 + r
  float b1v[4][4], b2v[4][4];
  #pragma unroll
  for (int t = 0; t < 4; t++)
    #pragma unroll
    for (int r = 0; r < 4; r++){
      b1v[t][r] = b1g[t*16 + l4*4 + r];
      b2v[t][r] = b2g[t*16 + l4*4 + r];
    }

  __syncthreads();

  const int irow = w*16 + l16;   // this wave's edge-row (B-frag col / C col)
  const int sw = l16 & 7;

  // layer 1: h^T = W1^T @ A1^T
  f32x4 acc[4] = {};
  #pragma unroll
  for (int ks = 0; ks < 2; ks++){
    int ch = ((ks*4 + l4) ^ sw) << 3;
    s16x8 bfrag = *(const s16x8*)(A1 + irow*64 + ch);
    #pragma unroll
    for (int t = 0; t < 4; t++){
      s16x8 afrag = *(const s16x8*)(Wl + (t*16 + l16)*64 + ch);
      acc[t] = __builtin_amdgcn_mfma_f32_16x16x32_bf16(afrag, bfrag, acc[t], 0, 0, 0);
    }
  }
  // epilogue: Hs[i][j] row-major, 4 contiguous j -> one b64 write
  {
    int off0 = irow*64 + (l4 & 1)*4;
    #pragma unroll
    for (int t = 0; t < 4; t++){
      float h0 = fmaxf(acc[t][0] + b1v[t][0], 0.0f);
      float h1 = fmaxf(acc[t][1] + b1v[t][1], 0.0f);
      float h2 = fmaxf(acc[t][2] + b1v[t][2], 0.0f);
      float h3 = fmaxf(acc[t][3] + b1v[t][3], 0.0f);
      int cj = 2*t + (l4 >> 1);
      *(uint2*)(Hs + off0 + ((cj ^ (irow & 7)) << 3)) =
          make_uint2(pk2(h0,h1), pk2(h2,h3));
    }
  }
  __syncthreads();

  // layer 2: msg^T = W2^T @ H^T
  f32x4 acc2[4] = {};
  #pragma unroll
  for (int ks = 0; ks < 2; ks++){
    int ch = ((ks*4 + l4) ^ sw) << 3;
    s16x8 bfrag = *(const s16x8*)(Hs + irow*64 + ch);
    #pragma unroll
    for (int t = 0; t < 4; t++){
      s16x8 afrag = *(const s16x8*)(Wl + 4096 + (t*16 + l16)*64 + ch);
      acc2[t] = __builtin_amdgcn_mfma_f32_16x16x32_bf16(afrag, bfrag, acc2[t], 0, 0, 0);
    }
  }
  // weighted column sums: agg[j] = sum_i relu(msg^T[j][i]+b2[j]) * wrow[i]
  {
    float wv = wrow[irow];     // i is fixed per thread
    #pragma unroll
    for (int t = 0; t < 4; t++){
      f32x4 p;
      #pragma unroll
      for (int r = 0; r < 4; r++){
        float m = fmaxf(acc2[t][r] + b2v[t][r], 0.0f) * wv;
        m += __shfl_xor(m, 1);
        m += __shfl_xor(m, 2);
        m += __shfl_xor(m, 4);
        m += __shfl_xor(m, 8);
        p[r] = m;
      }
      if (l16 == 0) *(f32x4*)&aggp[w][t*16 + l4*4] = p;
    }
  }
  __syncthreads();
  const int rowg = b*NV + v;
  if (tid < 64){
    float s = aggp[0][tid] + aggp[1][tid] + aggp[2][tid] + aggp[3][tid];
    out_aug[rowg*96 + 32 + tid] = s;
  } else if (tid < 96){
    out_aug[rowg*96 + (tid - 64)] = x[rowg*ND + (tid - 64)];
  }
}

// ---------------- kernel 2: node MLP + heads + logp --------------------------
// 32 rows per block (1024 blocks). fc1/fc2 transposed like k_msg; head direct.

__global__ __launch_bounds__(256) void k_node(
    const float* __restrict__ aug,
    const unsigned short* __restrict__ Fg,
    const float* __restrict__ f1b, const float* __restrict__ f2b,
    const float* __restrict__ mub, const float* __restrict__ lsb,
    float* __restrict__ out0, float* __restrict__ out1)
{
  __shared__ __align__(16) unsigned short A [32*128];  // [row][K=96 pad 128] swz
  __shared__ __align__(16) unsigned short H1[32*64];
  __shared__ __align__(16) unsigned short H2[32*64];
  __shared__ __align__(16) unsigned short Wn[1664*8];  // F1 | F2 | HW
  unsigned short* F1 = Wn;
  unsigned short* F2 = Wn + 8192;
  unsigned short* HW = Wn + 12288;

  const int tid = threadIdx.x;
  const int w = tid >> 6, lane = tid & 63;
  const int l16 = lane & 15, l4 = lane >> 4;
  const int g = blockIdx.x;

  // weights: 1664 chunks linear
  {
    char* lb = (char*)Wn + w*64*16;
    #pragma unroll
    for (int i = 0; i < 7; i++){
      if (i*256 + w*64 < 1664)     // wave-uniform predicate
        gload16(Fg + (i*256 + w*64 + lane)*8, lb + i*256*16);
    }
  }
  // A tile: 32 rows x 12 chunks from aug fp32 (pack in-flight)
  #pragma unroll
  for (int i = 0; i < 2; i++){
    int c = i*256 + tid;
    if (c < 384){
      int row = (c*683) >> 13;     // c/12
      int cc = c - row*12;
      const float4* s = (const float4*)(aug + (g*32 + row)*96 + cc*8);
      float4 a = s[0], bq = s[1];
      *(uint4*)(A + row*128 + ((cc ^ (row & 7)) << 3)) =
          make_uint4(pk2(a.x,a.y), pk2(a.z,a.w), pk2(bq.x,bq.y), pk2(bq.z,bq.w));
    }
  }
  __syncthreads();

  const int it = w & 1, jb = (w >> 1) * 32;  // wave -> (i-tile, j-halves)
  const int irow = it*16 + l16;
  const int sw = l16 & 7;

  float f1v[2][4], f2v[2][4];
  #pragma unroll
  for (int t = 0; t < 2; t++)
    #pragma unroll
    for (int r = 0; r < 4; r++){
      f1v[t][r] = f1b[jb + t*16 + l4*4 + r];
      f2v[t][r] = f2b[jb + t*16 + l4*4 + r];
    }

  // fc1 (K=96)
  f32x4 acc[2] = {};
  #pragma unroll
  for (int ks = 0; ks < 3; ks++){
    int ch = ((ks*4 + l4) ^ sw) << 3;
    s16x8 bfrag = *(const s16x8*)(A + irow*128 + ch);
    #pragma unroll
    for (int t = 0; t < 2; t++){
      s16x8 afrag = *(const s16x8*)(F1 + (jb + t*16 + l16)*128 + ch);
      acc[t] = __builtin_amdgcn_mfma_f32_16x16x32_bf16(afrag, bfrag, acc[t], 0, 0, 0);
    }
  }
  {
    int off0 = irow*64 + (l4 & 1)*4;
    #pragma unroll
    for (int t = 0; t < 2; t++){
      float h0 = fmaxf(acc[t][0] + f1v[t][0], 0.0f);
      float h1 = fmaxf(acc[t][1] + f1v[t][1], 0.0f);
      float h2 = fmaxf(acc[t][2] + f1v[t][2], 0.0f);
      float h3 = fmaxf(acc[t][3] + f1v[t][3], 0.0f);
      int j0 = jb + t*16 + l4*4;
      *(uint2*)(H1 + off0 + (((j0 >> 3) ^ (irow & 7)) << 3)) =
          make_uint2(pk2(h0,h1), pk2(h2,h3));
    }
  }
  __syncthreads();

  // fc2 (K=64)
  f32x4 acc2[2] = {};
  #pragma unroll
  for (int ks = 0; ks < 2; ks++){
    int ch = ((ks*4 + l4) ^ sw) << 3;
    s16x8 bfrag = *(const s16x8*)(H1 + irow*64 + ch);
    #pragma unroll
    for (int t = 0; t < 2; t++){
      s16x8 afrag = *(const s16x8*)(F2 + (jb + t*16 + l16)*64 + ch);
      acc2[t] = __builtin_amdgcn_mfma_f32_16x16x32_bf16(afrag, bfrag, acc2[t], 0, 0, 0);
    }
  }
  {
    int off0 = irow*64 + (l4 & 1)*4;
    #pragma unroll
    for (int t = 0; t < 2; t++){
      float h0 = fmaxf(acc2[t][0] + f2v[t][0], 0.0f);
      float h1 = fmaxf(acc2[t][1] + f2v[t][1], 0.0f);
      float h2 = fmaxf(acc2[t][2] + f2v[t][2], 0.0f);
      float h3 = fmaxf(acc2[t][3] + f2v[t][3], 0.0f);
      int j0 = jb + t*16 + l4*4;
      *(uint2*)(H2 + off0 + (((j0 >> 3) ^ (irow & 7)) << 3)) =
          make_uint2(pk2(h0,h1), pk2(h2,h3));
    }
  }
  __syncthreads();

  // head on waves 0,1: rows i = w*16.., cols: 0..7 mu, 8..15 ls
  if (w < 2){
    const int ir = w*16 + l16;
    f32x4 acc3 = {};
    #pragma unroll
    for (int ks = 0; ks < 2; ks++){
      int ch = ((ks*4 + l4) ^ sw) << 3;
      s16x8 a = *(const s16x8*)(H2 + ir*64 + ch);
      s16x8 bb = *(const s16x8*)(HW + l16*64 + ch);
      acc3 = __builtin_amdgcn_mfma_f32_16x16x32_bf16(a, bb, acc3, 0, 0, 0);
    }
    float bias = (l16 < 8) ? mub[l16] : lsb[l16 - 8];
    float term[4];
    #pragma unroll
    for (int r = 0; r < 4; r++){
      int grow = g*32 + w*16 + l4*4 + r;
      float val = acc3[r] + bias;
      if (l16 < 8){
        out0[grow*8 + l16] = tanhf(val);
        float xm = -2.0f * val;
        float sp = fmaxf(xm, 0.0f) + log1pf(expf(-fabsf(xm)));  // softplus(-2mu)
        term[r] = -2.0f * (LOG2C - val - sp);
      } else {
        float lsv = fminf(fmaxf(val, -3.0f), 1.0f);
        term[r] = -lsv - HLOG2PI;
      }
    }
    #pragma unroll
    for (int r = 0; r < 4; r++){
      term[r] += __shfl_xor(term[r], 1);
      term[r] += __shfl_xor(term[r], 2);
      term[r] += __shfl_xor(term[r], 4);
      term[r] += __shfl_xor(term[r], 8);
    }
    if (l16 == 0){
      #pragma unroll
      for (int r = 0; r < 4; r++) out1[g*32 + w*16 + l4*4 + r] = term[r];
    }
  }
}

// ---------------- launch -----------------------------------------------------

extern "C" void kernel_launch(void* const* d_in, const int* in_sizes, int n_in,
                              void* d_out, int out_size, void* d_ws, size_t ws_size,
                              hipStream_t stream) {
  const float* x     = (const float*)d_in[0];
  const float* edges = (const float*)d_in[1];
  const float* m1w   = (const float*)d_in[2];
  const float* m1b   = (const float*)d_in[3];
  const float* m2w   = (const float*)d_in[4];
  const float* m2b   = (const float*)d_in[5];
  const float* f1w   = (const float*)d_in[6];
  const float* f1b   = (const float*)d_in[7];
  const float* f2w   = (const float*)d_in[8];
  const float* f2b   = (const float*)d_in[9];
  const float* muw   = (const float*)d_in[10];
  const float* mub   = (const float*)d_in[11];
  const float* lsw   = (const float*)d_in[12];
  const float* lsb   = (const float*)d_in[13];
  const int*   send  = (const int*)d_in[14];
  const int*   recv  = (const int*)d_in[15];

  char* ws = (char*)d_ws;
  int* ebyv = (int*)ws;                                   // 16 KB
  int* sbyv = (int*)(ws + 16384);                         // 16 KB
  unsigned short* Wg  = (unsigned short*)(ws + 32768);    // 16 KB: W1 | W2
  unsigned short* Fg  = (unsigned short*)(ws + 49152);    // 26 KB: F1 | F2 | HW
  unsigned short* xbf = (unsigned short*)(ws + 75776);    // 2 MB bf16 x

  float* out0    = (float*)d_out;        // tanh(mu) [B,V,8]
  float* out1    = out0 + NB*NV*8;       // logp [B,V]
  float* out_aug = out1 + NB*NV;         // aug [B,V,96]

  k_bucket<<<1, 256, 0, stream>>>(recv, send, ebyv, sbyv);
  k_xbf<<<NB*NV*ND/2048, 256, 0, stream>>>(x, (uint4*)xbf);
  k_prep<<<dim3(24, 5), 256, 0, stream>>>(m1w, m2w, f1w, f2w, muw, lsw,
                                          Wg, Wg + 4096, Fg, Fg + 8192, Fg + 12288);
  k_msg<<<NB*NV, 256, 0, stream>>>(xbf, x, edges, ebyv, sbyv, Wg, m1b, m2b, out_aug);
  k_node<<<NB*NV/32, 256, 0, stream>>>(out_aug, Fg, f1b, f2b, mub, lsb, out0, out1);
}